// Round 1
// baseline (518.841 us; speedup 1.0000x reference)
//
#include <hip/hip_runtime.h>
#include <hip/hip_fp16.h>
#include <hip/hip_cooperative_groups.h>

namespace cg = cooperative_groups;

// Problem constants (match reference)
#define BB      2048
#define CC      1024
#define FF      128
#define NBLK    256      // blocks = CUs, cooperative-resident
#define RPB     8        // rows of K per block  (NBLK*RPB == BB)
#define TPB     256
#define NITER   10
#define SUBR    8        // colsum accumulator spreading (contention 256/8=32-way)
#define SCALING_F (2048.0f / 100000.0f)

// LDS budget: Kt 8*1028*4=32896 + dott 8*1024*2=16384 + vsh 4096 + capsh 4096
//             + ush/redsh small  => ~57.5 KB  (< 64 KB static limit, 1 block/CU)

__global__ void __launch_bounds__(TPB, 1)
sink_kernel(const int* __restrict__ users, const int* __restrict__ items,
            const float* __restrict__ D, const float* __restrict__ caps,
            const float* __restrict__ iemb, const float* __restrict__ uemb,
            float* __restrict__ out, float* __restrict__ scratch)
{
    cg::grid_group grid = cg::this_grid();
    const int bid = blockIdx.x;
    const int tid = threadIdx.x;
    const int r0  = bid * RPB;

    __shared__ float  Kt[RPB][CC + 4];   // +4 pad: colsum reads stride -> distinct banks
    __shared__ __half dott[RPB][CC];     // dotAll tile (fp16: rel err ~5e-4, budget is 2%)
    __shared__ float  vsh[CC];
    __shared__ float  capsh[CC];
    __shared__ float  ush[RPB];
    __shared__ float  redsh[TPB / 64];

    float* meanAcc = scratch;            // [0]
    float* colsum  = scratch + 16;       // [NITER][SUBR][CC]

    // ---- A0: zero scratch (harness poisons ws with 0xAA every call) ----
    {
        const int total = 16 + NITER * SUBR * CC;
        for (int i = bid * TPB + tid; i < total; i += NBLK * TPB)
            scratch[i] = 0.0f;
    }
    grid.sync();  // #1

    // ---- A1a: stage D tile into LDS, accumulate global mean(D) ----
    float psum = 0.0f;
    for (int i = tid; i < RPB * CC; i += TPB) {
        int r = i >> 10, c = i & (CC - 1);
        float d = D[((size_t)(r0 + r) << 10) + c];
        Kt[r][c] = d;
        psum += d;
    }
    {
        float w = psum;
        #pragma unroll
        for (int off = 32; off > 0; off >>= 1) w += __shfl_down(w, off, 64);
        if ((tid & 63) == 0) redsh[tid >> 6] = w;
        __syncthreads();
        if (tid == 0) {
            float s = 0.0f;
            #pragma unroll
            for (int k = 0; k < TPB / 64; ++k) s += redsh[k];
            atomicAdd(meanAcc, s);
        }
    }

    // ---- A1b: dotAll GEMM: dott[r][j] = ue[users[r0+r]] . iemb[j] ----
    // (items[b,c] in [0,CC) -> gather later from this row-local table)
    {
        int uidx[RPB];
        #pragma unroll
        for (int r = 0; r < RPB; ++r) uidx[r] = users[r0 + r];  // uniform -> s_load
        const float4* ie4 = (const float4*)iemb;
        for (int jj = 0; jj < CC / TPB; ++jj) {
            int j = jj * TPB + tid;
            float acc[RPB];
            #pragma unroll
            for (int r = 0; r < RPB; ++r) acc[r] = 0.0f;
            const float4* ip = ie4 + (size_t)j * (FF / 4);
            for (int f4 = 0; f4 < FF / 4; ++f4) {
                float4 a = ip[f4];
                #pragma unroll
                for (int r = 0; r < RPB; ++r) {
                    // wave-uniform address -> scalar load path, no VGPR cost
                    const float4* up = (const float4*)(uemb + (size_t)uidx[r] * FF);
                    float4 b = up[f4];
                    acc[r] += a.x * b.x + a.y * b.y + a.z * b.z + a.w * b.w;
                }
            }
            #pragma unroll
            for (int r = 0; r < RPB; ++r) dott[r][j] = __float2half(acc[r]);
        }
    }
    // caps staging + v0 = ones
    for (int c = tid; c < CC; c += TPB) {
        capsh[c] = caps[c] * SCALING_F;
        vsh[c]   = 1.0f;
    }
    grid.sync();  // #2  (mean complete; includes block barrier for LDS)

    // ---- B: K = exp(affinity/eps) = exp(5*dot - (5/mean)*D), in place ----
    {
        float s2 = 5.0f * (float)(BB * CC) / meanAcc[0];   // ALPHA/(EPS*mean)
        for (int i = tid; i < RPB * CC; i += TPB) {
            int r = i >> 10, c = i & (CC - 1);
            int it = items[((size_t)(r0 + r) << 10) + c];
            float d  = Kt[r][c];
            float dv = __half2float(dott[r][it]);
            Kt[r][c] = __expf(5.0f * dv - s2 * d);
        }
    }
    __syncthreads();

    // ---- C: 10 Sinkhorn iterations, 1 grid sync each ----
    for (int t = 0; t < NITER; ++t) {
        // u_r = 1 / (K v)_r : 32 lanes per row
        {
            int r = tid >> 5, l = tid & 31;
            float p = 0.0f;
            for (int c = l; c < CC; c += 32) p += Kt[r][c] * vsh[c];
            #pragma unroll
            for (int off = 16; off > 0; off >>= 1) p += __shfl_down(p, off, 32);
            if (l == 0) ush[r] = 1.0f / p;
        }
        __syncthreads();
        // partial column sums of K^T u -> spread atomic accumulators
        float* cb = colsum + ((size_t)t * SUBR + (bid & (SUBR - 1))) * CC;
        for (int c = tid; c < CC; c += TPB) {
            float s = 0.0f;
            #pragma unroll
            for (int r = 0; r < RPB; ++r) s += Kt[r][c] * ush[r];
            atomicAdd(&cb[c], s);
        }
        grid.sync();  // #3..#12
        // v = b / colsum  (computed redundantly per block)
        const float* base = colsum + (size_t)t * SUBR * CC;
        for (int c = tid; c < CC; c += TPB) {
            float s = 0.0f;
            #pragma unroll
            for (int k = 0; k < SUBR; ++k) s += base[k * CC + c];
            vsh[c] = capsh[c] / s;
        }
        __syncthreads();
    }

    grid.sync();  // #13: all colsum reads done (scratch may alias out)

    // ---- D: P = K * u (x) v ----
    for (int i = tid; i < RPB * CC; i += TPB) {
        int r = i >> 10, c = i & (CC - 1);
        out[((size_t)(r0 + r) << 10) + c] = Kt[r][c] * ush[r] * vsh[c];
    }
}

extern "C" void kernel_launch(void* const* d_in, const int* in_sizes, int n_in,
                              void* d_out, int out_size, void* d_ws, size_t ws_size,
                              hipStream_t stream) {
    const int*   users = (const int*)d_in[0];
    const int*   items = (const int*)d_in[1];
    const float* D     = (const float*)d_in[2];
    const float* caps  = (const float*)d_in[3];
    const float* iemb  = (const float*)d_in[4];
    const float* uemb  = (const float*)d_in[5];
    float* out = (float*)d_out;

    const size_t need = (size_t)(16 + NITER * SUBR * CC) * sizeof(float);
    // Fall back to d_out as scratch if ws is too small (final grid sync makes
    // the alias safe; Phase D fully overwrites out afterwards).
    float* scratch = (ws_size >= need) ? (float*)d_ws : out;

    void* args[] = { (void*)&users, (void*)&items, (void*)&D, (void*)&caps,
                     (void*)&iemb, (void*)&uemb, (void*)&out, (void*)&scratch };
    hipLaunchCooperativeKernel((void*)sink_kernel, dim3(NBLK), dim3(TPB),
                               args, 0, stream);
}

// Round 2
// 320.144 us; speedup vs baseline: 1.6206x; 1.6206x over previous
//
#include <hip/hip_runtime.h>
#include <hip/hip_fp16.h>

// Problem constants (match reference)
#define BB      2048
#define CC      1024
#define FF      128
#define NBLK    256      // blocks = CUs, cooperative-resident
#define RPB     8        // rows of K per block  (NBLK*RPB == BB)
#define TPB     256
#define NITER   10
#define SUBR    8        // spread counters/accumulators (256/8 = 32-way)
#define SCALING_F (2048.0f / 100000.0f)

// scratch layout (floats):
//   [0..255]   8 barrier counters, stride 32 floats (128 B apart)
//   [256]      meanAcc
//   [272.. ]   colsum[NITER][SUBR][CC]
#define SCRATCH_FLOATS (272 + NITER * SUBR * CC)

__global__ void init_kernel(float* __restrict__ scratch) {
    for (int i = blockIdx.x * blockDim.x + threadIdx.x; i < SCRATCH_FLOATS;
         i += gridDim.x * blockDim.x)
        scratch[i] = 0.0f;
}

// Hand-rolled grid barrier: monotonic spread counters, no CG overhead.
// Counters pre-zeroed by init_kernel (kernel boundary = bootstrap sync).
__device__ __forceinline__ void grid_barrier(unsigned* cnt, unsigned target,
                                             int bid) {
    __syncthreads();
    if (threadIdx.x == 0) {
        __threadfence();  // release: make this block's writes visible
        __hip_atomic_fetch_add(&cnt[(bid & (SUBR - 1)) * 32], 1u,
                               __ATOMIC_RELAXED, __HIP_MEMORY_SCOPE_AGENT);
        for (;;) {
            unsigned s = 0;
            #pragma unroll
            for (int g = 0; g < SUBR; ++g)
                s += __hip_atomic_load(&cnt[g * 32], __ATOMIC_RELAXED,
                                       __HIP_MEMORY_SCOPE_AGENT);
            if (s >= target) break;
            __builtin_amdgcn_s_sleep(2);
        }
        __threadfence();  // acquire: see other blocks' writes
    }
    __syncthreads();
}

// LDS: Kt 32896 + dott 16384 + vsh 4096 + capsh 4096 + uesh 4096 + misc
//      = ~61.6 KB  (< 64 KB static limit, 1 block/CU)
__global__ void __launch_bounds__(TPB, 1)
sink_kernel(const int* __restrict__ users, const int* __restrict__ items,
            const float* __restrict__ D, const float* __restrict__ caps,
            const float* __restrict__ iemb, const float* __restrict__ uemb,
            float* __restrict__ out, float* __restrict__ scratch)
{
    const int bid = blockIdx.x;
    const int tid = threadIdx.x;
    const int r0  = bid * RPB;

    __shared__ float  Kt[RPB][CC + 4];   // +4 pad keeps float4 alignment, breaks pow2 stride
    __shared__ __half dott[RPB][CC];     // dot table (fp16: rel err 5e-4 << 2% budget)
    __shared__ float  uesh[RPB][FF];     // user embeddings for this block's rows
    __shared__ float  vsh[CC];
    __shared__ float  capsh[CC];
    __shared__ float  ush[RPB];
    __shared__ float  redsh[TPB / 64];

    unsigned* barCnt = (unsigned*)scratch;
    float*    meanAcc = scratch + 256;
    float*    colsum  = scratch + 272;
    unsigned  barTgt  = 0;

    // ---- A1: stage D tile -> LDS (float4), accumulate global mean(D) ----
    float psum = 0.0f;
    {
        const float4* D4 = (const float4*)(D + ((size_t)r0 << 10));
        for (int i = tid; i < RPB * CC / 4; i += TPB) {
            float4 d = D4[i];
            int r = (i * 4) >> 10, c = (i * 4) & (CC - 1);
            *(float4*)&Kt[r][c] = d;
            psum += d.x + d.y + d.z + d.w;
        }
        float w = psum;
        #pragma unroll
        for (int off = 32; off > 0; off >>= 1) w += __shfl_down(w, off, 64);
        if ((tid & 63) == 0) redsh[tid >> 6] = w;
        __syncthreads();
        if (tid == 0) {
            float s = 0.0f;
            #pragma unroll
            for (int k = 0; k < TPB / 64; ++k) s += redsh[k];
            atomicAdd(meanAcc, s);
        }
    }

    // ---- A2: stage this block's 8 user embeddings -> LDS ----
    {
        int r = tid >> 5, f4 = tid & 31;                 // 256 threads = 8x32 float4
        int u = users[r0 + r];
        ((float4*)uesh[r])[f4] = ((const float4*)(uemb + (size_t)u * FF))[f4];
    }
    for (int c = tid; c < CC; c += TPB) {
        capsh[c] = caps[c] * SCALING_F;
        vsh[c]   = 1.0f;
    }
    __syncthreads();

    // ---- A3: dot GEMM: dott[r][j] = uesh[r] . iemb[j]  (iemb L2-hot) ----
    {
        const float4* us = (const float4*)uesh;          // [RPB][FF/4]
        for (int jj = 0; jj < CC / TPB; ++jj) {
            int j = jj * TPB + tid;
            float acc[RPB];
            #pragma unroll
            for (int r = 0; r < RPB; ++r) acc[r] = 0.0f;
            const float4* ip = (const float4*)(iemb + (size_t)j * FF);
            for (int f4 = 0; f4 < FF / 4; ++f4) {
                float4 a = ip[f4];
                #pragma unroll
                for (int r = 0; r < RPB; ++r) {
                    float4 b = us[r * (FF / 4) + f4];    // broadcast LDS read
                    acc[r] += a.x * b.x + a.y * b.y + a.z * b.z + a.w * b.w;
                }
            }
            #pragma unroll
            for (int r = 0; r < RPB; ++r) dott[r][j] = __float2half(acc[r]);
        }
    }

    barTgt += NBLK; grid_barrier(barCnt, barTgt, bid);   // meanAcc complete

    // ---- B: K = exp(5*dot - (5*B*C/sum(D)) * D), in place in Kt ----
    {
        float s2 = 5.0f * (float)(BB * CC) /
                   __hip_atomic_load(meanAcc, __ATOMIC_RELAXED, __HIP_MEMORY_SCOPE_AGENT);
        const int4* it4 = (const int4*)(items + ((size_t)r0 << 10));
        for (int i = tid; i < RPB * CC / 4; i += TPB) {
            int4 iv = it4[i];
            int r = (i * 4) >> 10, c = (i * 4) & (CC - 1);
            float4 d = *(float4*)&Kt[r][c];
            float4 kv;
            kv.x = __expf(5.0f * __half2float(dott[r][iv.x]) - s2 * d.x);
            kv.y = __expf(5.0f * __half2float(dott[r][iv.y]) - s2 * d.y);
            kv.z = __expf(5.0f * __half2float(dott[r][iv.z]) - s2 * d.z);
            kv.w = __expf(5.0f * __half2float(dott[r][iv.w]) - s2 * d.w);
            *(float4*)&Kt[r][c] = kv;
        }
    }
    __syncthreads();

    // ---- C: 10 Sinkhorn iterations, one hand-rolled barrier each ----
    for (int t = 0; t < NITER; ++t) {
        // u_r = 1/(K v)_r : 32 lanes per row, float4 LDS reads
        {
            int r = tid >> 5, l = tid & 31;
            const float4* kr = (const float4*)Kt[r];
            const float4* v4 = (const float4*)vsh;
            float p = 0.0f;
            for (int i = l; i < CC / 4; i += 32) {
                float4 k = kr[i], v = v4[i];
                p += k.x * v.x + k.y * v.y + k.z * v.z + k.w * v.w;
            }
            #pragma unroll
            for (int off = 16; off > 0; off >>= 1) p += __shfl_down(p, off, 32);
            if (l == 0) ush[r] = 1.0f / p;
        }
        __syncthreads();
        // partial column sums of K^T u -> spread global accumulators
        float* cb = colsum + ((size_t)t * SUBR + (bid & (SUBR - 1))) * CC;
        for (int c = tid; c < CC; c += TPB) {
            float s = 0.0f;
            #pragma unroll
            for (int r = 0; r < RPB; ++r) s += Kt[r][c] * ush[r];
            atomicAdd(&cb[c], s);
        }
        barTgt += NBLK; grid_barrier(barCnt, barTgt, bid);
        // v = b / colsum (redundant per block)
        const float* base = colsum + (size_t)t * SUBR * CC;
        for (int c = tid; c < CC; c += TPB) {
            float s = 0.0f;
            #pragma unroll
            for (int k = 0; k < SUBR; ++k) s += base[k * CC + c];
            vsh[c] = capsh[c] / s;
        }
        __syncthreads();
    }

    // all colsum reads done before P write (scratch may alias out)
    barTgt += NBLK; grid_barrier(barCnt, barTgt, bid);

    // ---- D: P = K * u (x) v, float4 stores ----
    {
        float4* o4 = (float4*)(out + ((size_t)r0 << 10));
        for (int i = tid; i < RPB * CC / 4; i += TPB) {
            int r = (i * 4) >> 10, c = (i * 4) & (CC - 1);
            float4 k = *(float4*)&Kt[r][c];
            float  ur = ush[r];
            float4 v = *(float4*)&vsh[c];
            float4 p;
            p.x = k.x * ur * v.x;  p.y = k.y * ur * v.y;
            p.z = k.z * ur * v.z;  p.w = k.w * ur * v.w;
            o4[i] = p;
        }
    }
}

extern "C" void kernel_launch(void* const* d_in, const int* in_sizes, int n_in,
                              void* d_out, int out_size, void* d_ws, size_t ws_size,
                              hipStream_t stream) {
    const int*   users = (const int*)d_in[0];
    const int*   items = (const int*)d_in[1];
    const float* D     = (const float*)d_in[2];
    const float* caps  = (const float*)d_in[3];
    const float* iemb  = (const float*)d_in[4];
    const float* uemb  = (const float*)d_in[5];
    float* out = (float*)d_out;

    const size_t need = (size_t)SCRATCH_FLOATS * sizeof(float);
    // Fall back to d_out as scratch if ws is too small (final barrier makes
    // the alias safe; Phase D fully overwrites out afterwards).
    float* scratch = (ws_size >= need) ? (float*)d_ws : out;

    hipLaunchKernelGGL(init_kernel, dim3(64), dim3(256), 0, stream, scratch);

    void* args[] = { (void*)&users, (void*)&items, (void*)&D, (void*)&caps,
                     (void*)&iemb, (void*)&uemb, (void*)&out, (void*)&scratch };
    hipLaunchCooperativeKernel((void*)sink_kernel, dim3(NBLK), dim3(TPB),
                               args, 0, stream);
}

// Round 3
// 192.590 us; speedup vs baseline: 2.6940x; 1.6623x over previous
//
#include <hip/hip_runtime.h>
#include <hip/hip_fp16.h>

// Problem constants (match reference)
#define BB      2048
#define CC      1024
#define FF      128
#define NBLK    256
#define RPB     8        // rows per block (NBLK*RPB == BB)
#define TPB     512      // 8 waves/CU
#define NITER   10
#define SUBR    8        // colsum accumulator spreading (256/8 = 32-way)
#define SCALING_F (2048.0f / 100000.0f)

// Static device storage: no hipMalloc, safe under graph capture, never
// poisoned by the harness (we fully rewrite every buffer every call).
__device__ float g_K[BB * CC];                 // 8 MB, IF-cache resident
__device__ float g_meanPart[NBLK];             // per-block D partial sums
__device__ float g_colsum[NITER * SUBR * CC];  // spread K^T u accumulators

// ---- K0: zero colsum + per-block partial sums of D -------------------------
__global__ void __launch_bounds__(TPB)
k0_prep(const float* __restrict__ D) {
    const int bid = blockIdx.x, tid = threadIdx.x;
    for (int i = bid * TPB + tid; i < NITER * SUBR * CC; i += NBLK * TPB)
        g_colsum[i] = 0.0f;
    const float4* D4 = (const float4*)D;
    float p = 0.0f;
    for (int i = bid * TPB + tid; i < BB * CC / 4; i += NBLK * TPB) {
        float4 d = D4[i];
        p += d.x + d.y + d.z + d.w;
    }
    #pragma unroll
    for (int off = 32; off > 0; off >>= 1) p += __shfl_down(p, off, 64);
    __shared__ float red[TPB / 64];
    if ((tid & 63) == 0) red[tid >> 6] = p;
    __syncthreads();
    if (tid == 0) {
        float s = 0.0f;
        #pragma unroll
        for (int k = 0; k < TPB / 64; ++k) s += red[k];
        g_meanPart[bid] = s;
    }
}

// ---- K1: dot GEMM + exp -> store K to global --------------------------------
// dott[r][j] = ue[users[r0+r]] . iemb[j]; K[b][c] = exp(5*dott[items] - s2*D)
__global__ void __launch_bounds__(TPB)
k1_buildK(const int* __restrict__ users, const int* __restrict__ items,
          const float* __restrict__ D, const float* __restrict__ iemb,
          const float* __restrict__ uemb) {
    const int bid = blockIdx.x, tid = threadIdx.x;
    const int r0 = bid * RPB;

    __shared__ float  uesh[RPB][FF];   // 4 KB
    __shared__ __half dott[RPB][CC];   // 16 KB
    __shared__ float  s2sh;

    if (tid < 256) {                   // stage 8 user embeddings (8x32 float4)
        int r = tid >> 5, f4 = tid & 31;
        int u = users[r0 + r];
        ((float4*)uesh[r])[f4] = ((const float4*)(uemb + (size_t)u * FF))[f4];
    }
    if (tid < 64) {                    // s2 = 5*B*C / sum(D), wave-0 reduce
        float s = g_meanPart[tid] + g_meanPart[tid + 64] +
                  g_meanPart[tid + 128] + g_meanPart[tid + 192];
        #pragma unroll
        for (int off = 32; off > 0; off >>= 1) s += __shfl_down(s, off, 64);
        if (tid == 0) s2sh = 5.0f * (float)(BB * CC) / s;
    }
    __syncthreads();

    // GEMM: each thread owns 2 candidate rows j; iemb stays L2-resident.
    const float4* us = (const float4*)uesh;
    #pragma unroll
    for (int jj = 0; jj < CC / TPB; ++jj) {
        int j = jj * TPB + tid;
        float acc[RPB] = {};
        const float4* ip = (const float4*)(iemb + (size_t)j * FF);
        for (int f4 = 0; f4 < FF / 4; ++f4) {
            float4 a = ip[f4];
            #pragma unroll
            for (int r = 0; r < RPB; ++r) {
                float4 b = us[r * (FF / 4) + f4];   // broadcast LDS read
                acc[r] += a.x * b.x + a.y * b.y + a.z * b.z + a.w * b.w;
            }
        }
        #pragma unroll
        for (int r = 0; r < RPB; ++r) dott[r][j] = __float2half(acc[r]);
    }
    __syncthreads();

    const float s2 = s2sh;
    const int4*   it4 = (const int4*)(items + ((size_t)r0 << 10));
    const float4* D4  = (const float4*)(D + ((size_t)r0 << 10));
    float4*       K4  = (float4*)(g_K + ((size_t)r0 << 10));
    for (int i = tid; i < RPB * CC / 4; i += TPB) {
        int4 iv = it4[i];
        float4 d = D4[i];
        int r = i >> 8;                // (i*4)>>10
        float4 kv;
        kv.x = __expf(5.0f * __half2float(dott[r][iv.x]) - s2 * d.x);
        kv.y = __expf(5.0f * __half2float(dott[r][iv.y]) - s2 * d.y);
        kv.z = __expf(5.0f * __half2float(dott[r][iv.z]) - s2 * d.z);
        kv.w = __expf(5.0f * __half2float(dott[r][iv.w]) - s2 * d.w);
        K4[i] = kv;
    }
}

// ---- K_iter(t): v_t -> u = 1/(K v_t) -> colsum[t] += K^T u ------------------
__global__ void __launch_bounds__(TPB)
k_iter(const float* __restrict__ caps, int t) {
    const int bid = blockIdx.x, tid = threadIdx.x;
    const int r0 = bid * RPB;

    __shared__ float Kt[RPB][CC];      // 32 KB
    __shared__ float vsh[CC];
    __shared__ float ush[RPB];

    // v_t (redundant per block); v_0 = 1
    for (int c = tid; c < CC; c += TPB) {
        float v = 1.0f;
        if (t > 0) {
            const float* base = g_colsum + (size_t)(t - 1) * SUBR * CC;
            float s = 0.0f;
            #pragma unroll
            for (int k = 0; k < SUBR; ++k) s += base[k * CC + c];
            v = caps[c] * SCALING_F / s;
        }
        vsh[c] = v;
    }
    // stage this block's K rows (coalesced float4, IF-hot)
    const float4* Kg = (const float4*)(g_K + ((size_t)r0 << 10));
    float4* KtL = (float4*)Kt;
    for (int i = tid; i < RPB * CC / 4; i += TPB) KtL[i] = Kg[i];
    __syncthreads();

    // u_r = 1/(K v)_r : one wave per row
    {
        int r = tid >> 6, l = tid & 63;
        const float4* kr = (const float4*)Kt[r];
        const float4* v4 = (const float4*)vsh;
        float p = 0.0f;
        #pragma unroll
        for (int i = 0; i < 4; ++i) {
            float4 k = kr[l + i * 64], v = v4[l + i * 64];
            p += k.x * v.x + k.y * v.y + k.z * v.z + k.w * v.w;
        }
        #pragma unroll
        for (int off = 32; off > 0; off >>= 1) p += __shfl_down(p, off, 64);
        if (l == 0) ush[r] = 1.0f / p;
    }
    __syncthreads();

    // colsum partials -> spread accumulators (fire-and-forget atomics)
    float* cb = g_colsum + ((size_t)t * SUBR + (bid & (SUBR - 1))) * CC;
    for (int c = tid; c < CC; c += TPB) {
        float s = 0.0f;
        #pragma unroll
        for (int r = 0; r < RPB; ++r) s += Kt[r][c] * ush[r];
        atomicAdd(&cb[c], s);
    }
}

// ---- K_final: u10 from v9 (colsum[8]), v10 from colsum[9], P = K*u(x)v ------
__global__ void __launch_bounds__(TPB)
k_final(const float* __restrict__ caps, float* __restrict__ out) {
    const int bid = blockIdx.x, tid = threadIdx.x;
    const int r0 = bid * RPB;

    __shared__ float Kt[RPB][CC];
    __shared__ float vsh[CC];
    __shared__ float ush[RPB];

    // v9
    for (int c = tid; c < CC; c += TPB) {
        const float* base = g_colsum + (size_t)(NITER - 2) * SUBR * CC;
        float s = 0.0f;
        #pragma unroll
        for (int k = 0; k < SUBR; ++k) s += base[k * CC + c];
        vsh[c] = caps[c] * SCALING_F / s;
    }
    const float4* Kg = (const float4*)(g_K + ((size_t)r0 << 10));
    float4* KtL = (float4*)Kt;
    for (int i = tid; i < RPB * CC / 4; i += TPB) KtL[i] = Kg[i];
    __syncthreads();

    // u10 = 1/(K v9)
    {
        int r = tid >> 6, l = tid & 63;
        const float4* kr = (const float4*)Kt[r];
        const float4* v4 = (const float4*)vsh;
        float p = 0.0f;
        #pragma unroll
        for (int i = 0; i < 4; ++i) {
            float4 k = kr[l + i * 64], v = v4[l + i * 64];
            p += k.x * v.x + k.y * v.y + k.z * v.z + k.w * v.w;
        }
        #pragma unroll
        for (int off = 32; off > 0; off >>= 1) p += __shfl_down(p, off, 64);
        if (l == 0) ush[r] = 1.0f / p;
    }
    __syncthreads();

    // v10 overwrites vsh
    for (int c = tid; c < CC; c += TPB) {
        const float* base = g_colsum + (size_t)(NITER - 1) * SUBR * CC;
        float s = 0.0f;
        #pragma unroll
        for (int k = 0; k < SUBR; ++k) s += base[k * CC + c];
        vsh[c] = caps[c] * SCALING_F / s;
    }
    __syncthreads();

    // P = K * u (x) v
    float4* o4 = (float4*)(out + ((size_t)r0 << 10));
    for (int i = tid; i < RPB * CC / 4; i += TPB) {
        int r = i >> 8;
        float4 k = KtL[i];
        float  ur = ush[r];
        float4 v = *(const float4*)&vsh[(i * 4) & (CC - 1)];
        float4 p;
        p.x = k.x * ur * v.x;  p.y = k.y * ur * v.y;
        p.z = k.z * ur * v.z;  p.w = k.w * ur * v.w;
        o4[i] = p;
    }
}

extern "C" void kernel_launch(void* const* d_in, const int* in_sizes, int n_in,
                              void* d_out, int out_size, void* d_ws, size_t ws_size,
                              hipStream_t stream) {
    const int*   users = (const int*)d_in[0];
    const int*   items = (const int*)d_in[1];
    const float* D     = (const float*)d_in[2];
    const float* caps  = (const float*)d_in[3];
    const float* iemb  = (const float*)d_in[4];
    const float* uemb  = (const float*)d_in[5];
    float* out = (float*)d_out;

    hipLaunchKernelGGL(k0_prep,   dim3(NBLK), dim3(TPB), 0, stream, D);
    hipLaunchKernelGGL(k1_buildK, dim3(NBLK), dim3(TPB), 0, stream,
                       users, items, D, iemb, uemb);
    for (int t = 0; t < NITER; ++t)
        hipLaunchKernelGGL(k_iter, dim3(NBLK), dim3(TPB), 0, stream, caps, t);
    hipLaunchKernelGGL(k_final,  dim3(NBLK), dim3(TPB), 0, stream, caps, out);
}